// Round 7
// baseline (163.435 us; speedup 1.0000x reference)
//
#include <hip/hip_runtime.h>
#include <hip/hip_bf16.h>
#include <math.h>

#define B_ 4
#define C_ 2
#define F_ 512
#define W_ 1024
#define NH_ 8
#define HD_ 64
#define ROT_ 32
#define NFREQ_ 16
#define BC_ (B_*C_)

// sqrt( (1/sqrt(512)) * log2(e) ): folded into Q and K so p = exp2(raw mfma dot)
#define QSC_ 0.2525048f

typedef short bf16x8 __attribute__((ext_vector_type(8)));
typedef float f32x4  __attribute__((ext_vector_type(4)));
typedef float f32x16 __attribute__((ext_vector_type(16)));
typedef unsigned short u16;
typedef unsigned int   u32;

#if __has_builtin(__builtin_amdgcn_exp2f)
#define EXP2(x) __builtin_amdgcn_exp2f(x)
#else
#define EXP2(x) exp2f(x)
#endif

// Explicit LDS-DMA drain before the publishing barrier (round-4 race fix):
// __syncthreads()' implicit drain does NOT reliably cover global_load_lds
// when consumers target a different LDS buffer (double-buffering).
#define VDRAIN() asm volatile("s_waitcnt vmcnt(0)" ::: "memory")

__device__ __forceinline__ u16 f2bf(float f) {
    union { float f; u32 u; } v; v.f = f;
    u32 r = (v.u + 0x7fffu + ((v.u >> 16) & 1u)) >> 16;
    return (u16)r;
}
__device__ __forceinline__ float bf2f(u16 h) {
    union { u32 u; float f; } v; v.u = ((u32)h) << 16;
    return v.f;
}
__device__ __forceinline__ f32x4 mfma16(bf16x8 a, bf16x8 b, f32x4 c) {
    return __builtin_amdgcn_mfma_f32_16x16x32_bf16(a, b, c, 0, 0, 0);
}
__device__ __forceinline__ f32x16 mfma32(bf16x8 a, bf16x8 b, f32x16 c) {
    return __builtin_amdgcn_mfma_f32_32x32x16_bf16(a, b, c, 0, 0, 0);
}
// async global->LDS, 16B per lane; lds base must be wave-uniform (HW adds lane*16)
__device__ __forceinline__ void gload16(const u16* g, u16* l) {
    __builtin_amdgcn_global_load_lds(
        (const __attribute__((address_space(1))) u32*)g,
        (__attribute__((address_space(3))) u32*)l, 16, 0, 0);
}
__device__ __forceinline__ u32 pk2(float lo, float hi) {
    __hip_bfloat162 h = __float22bfloat162_rn(make_float2(lo, hi));
    union { __hip_bfloat162 b; u32 u; } cv; cv.b = h; return cv.u;
}
// v_permlane32_swap: a[32:63] <-> b[0:31]
__device__ __forceinline__ void pl32swap(u32& a, u32& b) {
    asm volatile("v_permlane32_swap_b32 %0, %1" : "+v"(a), "+v"(b));
}

// ------- fused prep: wq->bf16, wo->hi/lo, trig table, x transpose+convert -------
__global__ __launch_bounds__(256)
void prep_all(const float* __restrict__ wq, const float* __restrict__ wo,
              const float* __restrict__ fp, const float* __restrict__ x,
              u16* __restrict__ wqh, u16* __restrict__ woh, u16* __restrict__ wol,
              float2* __restrict__ trig, u16* __restrict__ xh)
{
    __shared__ float T[64][65];
    const int b = blockIdx.x, t = threadIdx.x;
    if (b < 512) {                       // wq -> bf16 hi only
        int i = (b * 256 + t) * 4;
        float4 v = *(const float4*)(wq + i);
        ushort4 h;
        h.x = f2bf(v.x); h.y = f2bf(v.y); h.z = f2bf(v.z); h.w = f2bf(v.w);
        *(ushort4*)(wqh + i) = h;
    } else if (b < 1024) {               // wo -> hi/lo split
        int i = ((b - 512) * 256 + t) * 4;
        float4 v = *(const float4*)(wo + i);
        ushort4 h, l;
        h.x = f2bf(v.x); l.x = f2bf(v.x - bf2f(h.x));
        h.y = f2bf(v.y); l.y = f2bf(v.y - bf2f(h.y));
        h.z = f2bf(v.z); l.z = f2bf(v.z - bf2f(h.z));
        h.w = f2bf(v.w); l.w = f2bf(v.w - bf2f(h.w));
        *(ushort4*)(woh + i) = h;
        *(ushort4*)(wol + i) = l;
    } else if (b < 1088) {               // trig: 64 blocks x 256 = 16384 entries
        int idx = (b - 1024) * 256 + t;
        int w = idx >> 4, j = idx & 15;
        float th = (float)w * fp[j];
        float s, c;
        sincosf(th, &s, &c);
        trig[idx] = make_float2(c, s);
    } else {                             // x[bc][h][w] -> x_t[bc][w][h] bf16
        const int b2 = b - 1088;         // 1024 blocks: (8 hb, 16 wb, 8 bc)
        const int h0 = (b2 & 7) * 64, w0 = ((b2 >> 3) & 15) * 64, bc = b2 >> 7;
        {
            const int hl = t >> 2, wc = (t & 3) * 16;
            const float* src = x + ((size_t)bc * F_ + h0 + hl) * W_ + w0 + wc;
            #pragma unroll
            for (int z = 0; z < 4; ++z)
                *(float4*)(&T[hl][wc + z * 4]) = *(const float4*)(src + z * 4);
        }
        __syncthreads();
        {
            const int wl = t >> 2, hc = (t & 3) * 16;
            u16 hv[16];
            #pragma unroll
            for (int z = 0; z < 16; ++z) hv[z] = f2bf(T[hc + z][wl]);
            size_t base = ((size_t)bc * W_ + w0 + wl) * F_ + h0 + hc;
            *(uint4*)(xh + base)     = *(uint4*)(hv);
            *(uint4*)(xh + base + 8) = *(uint4*)(hv + 8);
        }
    }
}

// ---------------- MFMA GEMM, 64x128 tile, dbuf prefetch, explicit drains -------
// D[g][w] = sum_h A[g][h] * Bt[w][h].  4 waves: wm=wid>>1, wn=wid&1; wave = 32x64 out.
// Grid (8,8,8) = 512 blocks -> 2/CU.
// MODE 0: single bf16 pass (A=wq hi); writes V raw + Q rope'd q_t[bc][head][w][dd]
// MODE 1: 2-pass (A hi + A lo) x (B hi);  B-lo path DROPPED (error ~1e-5, see R7 notes);
//         writes fp32 out
// LDS buffer (u16): A_hi[64][32] @0 | (MODE1) A_lo @2048 | B_hi[128][32] @B_OFF
// swizzle: 16B slot ^= (row>>1)&3  (stage source + frag read; 2 lanes/bank = free)
template<int MODE>
__global__ __launch_bounds__(256)
void gemm4(const u16* __restrict__ Ah_, const u16* __restrict__ Al_,
           const u16* __restrict__ Bh_,
           u16* __restrict__ Vout, u16* __restrict__ Qout,
           float* __restrict__ Fout, const float2* __restrict__ trig)
{
    constexpr int BUFS  = MODE ? 8192 : 6144;     // u16 per buffer
    constexpr int B_OFF = MODE ? 4096 : 2048;
    __shared__ u16 sh[2 * BUFS];                  // MODE1 32KB, MODE0 24KB

    const int tid = threadIdx.x, lane = tid & 63, wid = tid >> 6;
    const int wm = wid >> 1, wn = wid & 1;
    const int m0 = blockIdx.x * 64, n0 = blockIdx.y * 128, bc = blockIdx.z, c = bc % C_;
    const u16* Abh = Ah_ + (size_t)c * F_ * F_;
    const u16* Abl = MODE ? (Al_ + (size_t)c * F_ * F_) : (const u16*)nullptr;
    const u16* Bbh = Bh_ + (size_t)bc * W_ * F_;

    f32x4 acc[2][4] = {};
    const int srow = tid >> 2, sslot = tid & 3;

    auto STAGE = [&](int k0, int buf) {
        u16* base = sh + buf * BUFS;
        {   // A: 64 rows x 4 slots (1/lane each tile)
            const int ts = sslot ^ ((srow >> 1) & 3);
            const size_t ga = (size_t)(m0 + srow) * F_ + k0 + ts * 8;
            gload16(Abh + ga, base + wid * 512);
            if constexpr (MODE) gload16(Abl + ga, base + 2048 + wid * 512);
        }
        #pragma unroll
        for (int h = 0; h < 2; ++h) {   // B: 128 rows (2/lane)
            const int brow = h * 64 + srow;
            const int ts = sslot ^ ((brow >> 1) & 3);
            const size_t gb = (size_t)(n0 + brow) * F_ + k0 + ts * 8;
            gload16(Bbh + gb, base + B_OFF + h * 2048 + wid * 512);
        }
    };

    STAGE(0, 0);
    VDRAIN();                // own DMA landed in buf 0
    __syncthreads();         // publish buf 0
    int cur = 0;
    for (int kt = 0; kt < 16; ++kt) {
        if (kt < 15) STAGE((kt + 1) * 32, cur ^ 1);   // flies during compute
        const u16* Ash = sh + cur * BUFS;
        const u16* Asl = Ash + 2048;
        const u16* Bsh = Ash + B_OFF;

        bf16x8 fah[2], fal[2];
        #pragma unroll
        for (int i = 0; i < 2; ++i) {
            const int row = wm * 32 + i * 16 + (lane & 15);
            const int idx = row * 32 + (((lane >> 4) ^ ((row >> 1) & 3)) << 3);
            fah[i] = *(const bf16x8*)(&Ash[idx]);
            if constexpr (MODE) fal[i] = *(const bf16x8*)(&Asl[idx]);
        }
        #pragma unroll
        for (int j = 0; j < 4; ++j) {
            const int rowb = wn * 64 + j * 16 + (lane & 15);
            const int idxb = rowb * 32 + (((lane >> 4) ^ ((rowb >> 1) & 3)) << 3);
            bf16x8 bh = *(const bf16x8*)(&Bsh[idxb]);
            #pragma unroll
            for (int i = 0; i < 2; ++i)
                acc[i][j] = mfma16(fah[i], bh, acc[i][j]);
            if constexpr (MODE) {
                #pragma unroll
                for (int i = 0; i < 2; ++i)
                    acc[i][j] = mfma16(fal[i], bh, acc[i][j]);
            }
        }
        VDRAIN();            // own prefetch landed before buffer becomes readable
        __syncthreads();     // publish cur^1; all reads of cur done
        cur ^= 1;
    }

    // C/D frag: row = (lane>>4)*4 + r, col = lane&15
    #pragma unroll
    for (int i = 0; i < 2; ++i) {
        const int gr = m0 + wm * 32 + i * 16 + (lane >> 4) * 4;
        #pragma unroll
        for (int j = 0; j < 4; ++j) {
            const int wc = n0 + wn * 64 + j * 16 + (lane & 15);
            #pragma unroll
            for (int r = 0; r < 4; ++r) {
                const size_t ad = ((size_t)bc * F_ + gr + r) * W_ + wc;
                if constexpr (MODE == 1) Fout[ad] = acc[i][j][r];
                else                     Vout[ad] = f2bf(acc[i][j][r]);
            }
        }
    }

    if constexpr (MODE == 0) {
        // rope in-register, per-wave LDS transpose (wave owns 32 dd x 64 w),
        // write q_t[bc][head][w][dd].  M-tile (64) == one head: head = blockIdx.x.
        __syncthreads();                      // staging LDS dead
        u16* Qt = sh + wid * 2048;            // [64 w][32 dd], slot ^= wl&3
        const int head = blockIdx.x;
        #pragma unroll
        for (int j = 0; j < 4; ++j) {
            const int wl = j * 16 + (lane & 15);
            const int wg = n0 + wn * 64 + wl;
            #pragma unroll
            for (int i = 0; i < 2; ++i) {
                float q[4];
                if (wm == 0) {                // dd < 32: rotate
                    #pragma unroll
                    for (int p = 0; p < 2; ++p) {
                        const int fidx = i * 8 + (lane >> 4) * 2 + p;
                        float2 cs = trig[wg * NFREQ_ + fidx];
                        float e = acc[i][j][2 * p], o = acc[i][j][2 * p + 1];
                        q[2 * p]     = (e * cs.x - o * cs.y) * QSC_;
                        q[2 * p + 1] = (o * cs.x + e * cs.y) * QSC_;
                    }
                } else {
                    #pragma unroll
                    for (int r = 0; r < 4; ++r) q[r] = acc[i][j][r] * QSC_;
                }
                #pragma unroll
                for (int r = 0; r < 4; ++r) {
                    const int ddl = i * 16 + (lane >> 4) * 4 + r;     // [0,32)
                    Qt[wl * 32 + ((ddl & 7) | (((ddl >> 3) ^ (wl & 3)) << 3))] = f2bf(q[r]);
                }
            }
        }
        // same-wave read-back (compiler orders lgkmcnt), 16B writes
        const size_t qrow = (((size_t)bc * NH_ + head) * W_ + n0 + wn * 64 + lane) * 64 + wm * 32;
        #pragma unroll
        for (int s = 0; s < 4; ++s) {
            uint4 v = *(const uint4*)(&Qt[lane * 32 + ((s ^ (lane & 3)) << 3)]);
            *(uint4*)(&Qout[qrow + s * 8]) = v;
        }
    }
}

// ---------------- transposed 32x32-MFMA flash attention ----------------
// 2-wave blocks (64 q-cols each); K-frags read DIRECTLY from global (L2-resident,
// K == Q tensor) -> no K LDS tile, half the ds_reads, VMEM pipe does the work.
// V double-buffered in LDS (16 KB total). p = exp2(s), no max-sub.
// Writes a_t hi ONLY: [bc][w][512].
__global__ __launch_bounds__(128)
void attn4(const u16* __restrict__ Qt, const u16* __restrict__ Vg,
           u16* __restrict__ AhO)
{
    __shared__ u16 sh[8192];      // Vs dbuf: 2 x [64 d][64 k] u16, slot^(row&7)
    const int tid = threadIdx.x, lane = tid & 63, wid = tid >> 6;   // wid 0..1
    const int q0 = blockIdx.x * 64, head = blockIdx.y, bc = blockIdx.z;
    const u16* qb = Qt + ((size_t)bc * NH_ + head) * W_ * 64;
    const u16* vb = Vg + ((size_t)bc * F_ + head * HD_) * W_;

    const int qcol = lane & 31, hi = lane >> 5;
    const int srow = lane >> 3, st = lane & 7;

    // hoisted Q B-frags: lane&31 = q col, d = ks*16 + hi*8 + j
    bf16x8 qf[4];
    {
        const u16* qrow = qb + (size_t)(q0 + wid * 32 + qcol) * 64 + hi * 8;
        #pragma unroll
        for (int ks = 0; ks < 4; ++ks)
            qf[ks] = *(const bf16x8*)(qrow + ks * 16);
    }

    f32x16 o0, o1;
    #pragma unroll
    for (int i = 0; i < 16; ++i) { o0[i] = 0.f; o1[i] = 0.f; }
    float lsum = 0.f;

    auto STAGE = [&](int kt, int buf) {
        const int k0 = kt * 64;
        u16* Vsb = sh + buf * 4096;
        #pragma unroll
        for (int p = 0; p < 4; ++p) {
            const int rb = wid * 32 + p * 8;          // wave-uniform
            const int r  = rb + srow;
            const int ts = st ^ (r & 7);
            gload16(vb + (size_t)r * W_ + k0 + ts * 8, Vsb + rb * 64);
        }
    };

    STAGE(0, 0);
    VDRAIN();                 // own DMA (and qf loads) landed
    __syncthreads();          // publish buf 0
    int cur = 0;
    for (int kt = 0; kt < 16; ++kt) {
        if (kt < 15) STAGE(kt + 1, cur ^ 1);   // V prefetch flies during compute
        const u16* Vs = sh + cur * 4096;
        const int k0 = kt * 64;

        // S^T = K . Q^T over d (4 K=16 steps); K-frags straight from global/L2
        f32x16 s0, s1;
        #pragma unroll
        for (int i = 0; i < 16; ++i) { s0[i] = 0.f; s1[i] = 0.f; }
        #pragma unroll
        for (int ks = 0; ks < 4; ++ks) {
            const int sl = ks * 2 + hi;
            bf16x8 kf0 = *(const bf16x8*)(qb + (size_t)(k0 + qcol) * 64 + sl * 8);
            bf16x8 kf1 = *(const bf16x8*)(qb + (size_t)(k0 + 32 + qcol) * 64 + sl * 8);
            s0 = mfma32(kf0, qf[ks], s0);
            s1 = mfma32(kf1, qf[ks], s1);
        }

        // p = exp2(s); accumulate denominator
        float p0[16], p1[16];
        #pragma unroll
        for (int i = 0; i < 16; ++i) { p0[i] = EXP2(s0[i]); p1[i] = EXP2(s1[i]); }
        float part = 0.f;
        #pragma unroll
        for (int i = 0; i < 16; ++i) part += p0[i] + p1[i];
        lsum += part;

        // 4 P^T B-frags in-register (cvt_pk + permlane32_swap)
        bf16x8 pf[4];
        #pragma unroll
        for (int kb = 0; kb < 2; ++kb) {
            const float* pp = kb ? p1 : p0;
            #pragma unroll
            for (int f = 0; f < 2; ++f) {
                u32 a1 = pk2(pp[f*8+0], pp[f*8+1]);
                u32 a2 = pk2(pp[f*8+2], pp[f*8+3]);
                u32 b1 = pk2(pp[f*8+4], pp[f*8+5]);
                u32 b2 = pk2(pp[f*8+6], pp[f*8+7]);
                pl32swap(a1, b1);
                pl32swap(a2, b2);
                union { u32 w[4]; bf16x8 v; } u;
                u.w[0] = a1; u.w[1] = a2; u.w[2] = b1; u.w[3] = b2;
                pf[kb * 2 + f] = u.v;
            }
        }

        // O^T += V^T . P^T
        #pragma unroll
        for (int ks2 = 0; ks2 < 4; ++ks2) {
            const int sl = ks2 * 2 + hi;
            const int d0r = qcol;
            const int d1r = 32 + qcol;
            bf16x8 vf0 = *(const bf16x8*)(Vs + d0r * 64 + ((sl ^ (d0r & 7)) << 3));
            bf16x8 vf1 = *(const bf16x8*)(Vs + d1r * 64 + ((sl ^ (d1r & 7)) << 3));
            o0 = mfma32(vf0, pf[ks2], o0);
            o1 = mfma32(vf1, pf[ks2], o1);
        }
        VDRAIN();            // own V prefetch landed before buffer becomes readable
        __syncthreads();     // publish cur^1; all reads of cur done
        cur ^= 1;
    }

    lsum += __shfl_xor(lsum, 32);
    const float inv = 1.f / lsum;

    const int wrow = q0 + wid * 32 + qcol;
    const size_t rowbase = ((size_t)bc * W_ + wrow) * F_ + head * HD_;
    #pragma unroll
    for (int dblk = 0; dblk < 2; ++dblk) {
        const f32x16 ov = dblk ? o1 : o0;
        const int coloff = dblk * 32;
        #pragma unroll
        for (int pr = 0; pr < 8; ++pr) {      // reg pair (2pr,2pr+1) -> d rows
            const float v1 = ov[2 * pr]     * inv;
            const float v2 = ov[2 * pr + 1] * inv;
            const int drow = ((2 * pr) & 3) + 8 * (pr >> 1) + 4 * hi;
            const u16 h1 = f2bf(v1), h2 = f2bf(v2);
            *(u32*)(AhO + rowbase + coloff + drow) = (u32)h1 | ((u32)h2 << 16);
        }
    }
}

extern "C" void kernel_launch(void* const* d_in, const int* in_sizes, int n_in,
                              void* d_out, int out_size, void* d_ws, size_t ws_size,
                              hipStream_t stream) {
    const float* x  = (const float*)d_in[0];
    const float* wq = (const float*)d_in[1];   // reference: q, k, v ALL from wq
    const float* wo = (const float*)d_in[4];
    const float* fp = (const float*)d_in[5];
    float* out = (float*)d_out;

    char* w8 = (char*)d_ws;
    const size_t MB = 1024 * 1024;
    u16* xh   = (u16*)(w8);                    // 8 MB  x_t[bc][w][h] bf16
    u16* wqh  = (u16*)(w8 + 8 * MB);           // 1 MB
    u16* woh  = (u16*)(w8 + 9 * MB);           // 1 MB
    u16* wol  = (u16*)(w8 + 10 * MB);          // 1 MB
    float2* trig = (float2*)(w8 + 11 * MB);    // 128 KB
    u16* qbuf = (u16*)(w8 + 12 * MB);          // 8 MB  q_t[bc][head][w][64]
    u16* vbuf = (u16*)(w8 + 20 * MB);          // 8 MB  v[bc][g][w]
    u16* ah   = xh;                            // alias: x_t dead after proj GEMM

    prep_all<<<2112, 256, 0, stream>>>(wq, wo, fp, x, wqh, woh, wol, trig, xh);

    gemm4<0><<<dim3(8, 8, 8), 256, 0, stream>>>(
        wqh, nullptr, xh, vbuf, qbuf, nullptr, trig);

    attn4<<<dim3(16, NH_, BC_), 128, 0, stream>>>(qbuf, vbuf, ah);

    gemm4<1><<<dim3(8, 8, 8), 256, 0, stream>>>(
        woh, wol, ah, nullptr, nullptr, out, trig);
}

// Round 8
// 143.837 us; speedup vs baseline: 1.1363x; 1.1363x over previous
//
#include <hip/hip_runtime.h>
#include <hip/hip_bf16.h>
#include <math.h>

#define B_ 4
#define C_ 2
#define F_ 512
#define W_ 1024
#define NH_ 8
#define HD_ 64
#define ROT_ 32
#define NFREQ_ 16
#define BC_ (B_*C_)

// sqrt( (1/sqrt(512)) * log2(e) ): folded into Q and K so p = exp2(raw mfma dot)
#define QSC_ 0.2525048f

typedef short bf16x8 __attribute__((ext_vector_type(8)));
typedef float f32x4  __attribute__((ext_vector_type(4)));
typedef float f32x16 __attribute__((ext_vector_type(16)));
typedef unsigned short u16;
typedef unsigned int   u32;

#if __has_builtin(__builtin_amdgcn_exp2f)
#define EXP2(x) __builtin_amdgcn_exp2f(x)
#else
#define EXP2(x) exp2f(x)
#endif

// Explicit LDS-DMA drain before the publishing barrier (round-4 race fix):
// __syncthreads()' implicit drain does NOT reliably cover global_load_lds
// when consumers target a different LDS buffer (double-buffering).
#define VDRAIN() asm volatile("s_waitcnt vmcnt(0)" ::: "memory")

__device__ __forceinline__ u16 f2bf(float f) {
    union { float f; u32 u; } v; v.f = f;
    u32 r = (v.u + 0x7fffu + ((v.u >> 16) & 1u)) >> 16;
    return (u16)r;
}
__device__ __forceinline__ float bf2f(u16 h) {
    union { u32 u; float f; } v; v.u = ((u32)h) << 16;
    return v.f;
}
__device__ __forceinline__ f32x4 mfma16(bf16x8 a, bf16x8 b, f32x4 c) {
    return __builtin_amdgcn_mfma_f32_16x16x32_bf16(a, b, c, 0, 0, 0);
}
__device__ __forceinline__ f32x16 mfma32(bf16x8 a, bf16x8 b, f32x16 c) {
    return __builtin_amdgcn_mfma_f32_32x32x16_bf16(a, b, c, 0, 0, 0);
}
// async global->LDS, 16B per lane; lds base must be wave-uniform (HW adds lane*16)
__device__ __forceinline__ void gload16(const u16* g, u16* l) {
    __builtin_amdgcn_global_load_lds(
        (const __attribute__((address_space(1))) u32*)g,
        (__attribute__((address_space(3))) u32*)l, 16, 0, 0);
}
__device__ __forceinline__ u32 pk2(float lo, float hi) {
    __hip_bfloat162 h = __float22bfloat162_rn(make_float2(lo, hi));
    union { __hip_bfloat162 b; u32 u; } cv; cv.b = h; return cv.u;
}
// v_permlane32_swap: a[32:63] <-> b[0:31]
__device__ __forceinline__ void pl32swap(u32& a, u32& b) {
    asm volatile("v_permlane32_swap_b32 %0, %1" : "+v"(a), "+v"(b));
}

// ------- fused prep: wq->bf16, wo->hi/lo, trig table, x transpose+convert -------
__global__ __launch_bounds__(256)
void prep_all(const float* __restrict__ wq, const float* __restrict__ wo,
              const float* __restrict__ fp, const float* __restrict__ x,
              u16* __restrict__ wqh, u16* __restrict__ woh, u16* __restrict__ wol,
              float2* __restrict__ trig, u16* __restrict__ xh)
{
    __shared__ float T[64][65];
    const int b = blockIdx.x, t = threadIdx.x;
    if (b < 512) {                       // wq -> bf16 hi only
        int i = (b * 256 + t) * 4;
        float4 v = *(const float4*)(wq + i);
        ushort4 h;
        h.x = f2bf(v.x); h.y = f2bf(v.y); h.z = f2bf(v.z); h.w = f2bf(v.w);
        *(ushort4*)(wqh + i) = h;
    } else if (b < 1024) {               // wo -> hi/lo split
        int i = ((b - 512) * 256 + t) * 4;
        float4 v = *(const float4*)(wo + i);
        ushort4 h, l;
        h.x = f2bf(v.x); l.x = f2bf(v.x - bf2f(h.x));
        h.y = f2bf(v.y); l.y = f2bf(v.y - bf2f(h.y));
        h.z = f2bf(v.z); l.z = f2bf(v.z - bf2f(h.z));
        h.w = f2bf(v.w); l.w = f2bf(v.w - bf2f(h.w));
        *(ushort4*)(woh + i) = h;
        *(ushort4*)(wol + i) = l;
    } else if (b < 1088) {               // trig: 64 blocks x 256 = 16384 entries
        int idx = (b - 1024) * 256 + t;
        int w = idx >> 4, j = idx & 15;
        float th = (float)w * fp[j];
        float s, c;
        sincosf(th, &s, &c);
        trig[idx] = make_float2(c, s);
    } else {                             // x[bc][h][w] -> x_t[bc][w][h] bf16
        const int b2 = b - 1088;         // 1024 blocks: (8 hb, 16 wb, 8 bc)
        const int h0 = (b2 & 7) * 64, w0 = ((b2 >> 3) & 15) * 64, bc = b2 >> 7;
        {
            const int hl = t >> 2, wc = (t & 3) * 16;
            const float* src = x + ((size_t)bc * F_ + h0 + hl) * W_ + w0 + wc;
            #pragma unroll
            for (int z = 0; z < 4; ++z)
                *(float4*)(&T[hl][wc + z * 4]) = *(const float4*)(src + z * 4);
        }
        __syncthreads();
        {
            const int wl = t >> 2, hc = (t & 3) * 16;
            u16 hv[16];
            #pragma unroll
            for (int z = 0; z < 16; ++z) hv[z] = f2bf(T[hc + z][wl]);
            size_t base = ((size_t)bc * W_ + w0 + wl) * F_ + h0 + hc;
            *(uint4*)(xh + base)     = *(uint4*)(hv);
            *(uint4*)(xh + base + 8) = *(uint4*)(hv + 8);
        }
    }
}

// ---------------- MFMA GEMM, 64x128 tile, dbuf prefetch, explicit drains -------
// D[g][w] = sum_h A[g][h] * Bt[w][h].  4 waves: wm=wid>>1, wn=wid&1; wave = 32x64 out.
// Grid (8,8,8) = 512 blocks -> 2/CU.
// MODE 0: single bf16 pass (A=wq hi); writes V raw + Q rope'd q_t[bc][head][w][dd]
// MODE 1: 2-pass (A hi + A lo) x (B hi); B-lo dropped (error ~1e-5); writes fp32 out
// LDS buffer (u16): A_hi[64][32] @0 | (MODE1) A_lo @2048 | B_hi[128][32] @B_OFF
// swizzle: 16B slot ^= (row>>1)&3  (stage source + frag read; 2 lanes/bank = free)
template<int MODE>
__global__ __launch_bounds__(256)
void gemm4(const u16* __restrict__ Ah_, const u16* __restrict__ Al_,
           const u16* __restrict__ Bh_,
           u16* __restrict__ Vout, u16* __restrict__ Qout,
           float* __restrict__ Fout, const float2* __restrict__ trig)
{
    constexpr int BUFS  = MODE ? 8192 : 6144;     // u16 per buffer
    constexpr int B_OFF = MODE ? 4096 : 2048;
    __shared__ u16 sh[2 * BUFS];                  // MODE1 32KB, MODE0 24KB

    const int tid = threadIdx.x, lane = tid & 63, wid = tid >> 6;
    const int wm = wid >> 1, wn = wid & 1;
    const int m0 = blockIdx.x * 64, n0 = blockIdx.y * 128, bc = blockIdx.z, c = bc % C_;
    const u16* Abh = Ah_ + (size_t)c * F_ * F_;
    const u16* Abl = MODE ? (Al_ + (size_t)c * F_ * F_) : (const u16*)nullptr;
    const u16* Bbh = Bh_ + (size_t)bc * W_ * F_;

    f32x4 acc[2][4] = {};
    const int srow = tid >> 2, sslot = tid & 3;

    auto STAGE = [&](int k0, int buf) {
        u16* base = sh + buf * BUFS;
        {   // A: 64 rows x 4 slots (1/lane each tile)
            const int ts = sslot ^ ((srow >> 1) & 3);
            const size_t ga = (size_t)(m0 + srow) * F_ + k0 + ts * 8;
            gload16(Abh + ga, base + wid * 512);
            if constexpr (MODE) gload16(Abl + ga, base + 2048 + wid * 512);
        }
        #pragma unroll
        for (int h = 0; h < 2; ++h) {   // B: 128 rows (2/lane)
            const int brow = h * 64 + srow;
            const int ts = sslot ^ ((brow >> 1) & 3);
            const size_t gb = (size_t)(n0 + brow) * F_ + k0 + ts * 8;
            gload16(Bbh + gb, base + B_OFF + h * 2048 + wid * 512);
        }
    };

    STAGE(0, 0);
    VDRAIN();                // own DMA landed in buf 0
    __syncthreads();         // publish buf 0
    int cur = 0;
    for (int kt = 0; kt < 16; ++kt) {
        if (kt < 15) STAGE((kt + 1) * 32, cur ^ 1);   // flies during compute
        const u16* Ash = sh + cur * BUFS;
        const u16* Asl = Ash + 2048;
        const u16* Bsh = Ash + B_OFF;

        bf16x8 fah[2], fal[2];
        #pragma unroll
        for (int i = 0; i < 2; ++i) {
            const int row = wm * 32 + i * 16 + (lane & 15);
            const int idx = row * 32 + (((lane >> 4) ^ ((row >> 1) & 3)) << 3);
            fah[i] = *(const bf16x8*)(&Ash[idx]);
            if constexpr (MODE) fal[i] = *(const bf16x8*)(&Asl[idx]);
        }
        #pragma unroll
        for (int j = 0; j < 4; ++j) {
            const int rowb = wn * 64 + j * 16 + (lane & 15);
            const int idxb = rowb * 32 + (((lane >> 4) ^ ((rowb >> 1) & 3)) << 3);
            bf16x8 bh = *(const bf16x8*)(&Bsh[idxb]);
            #pragma unroll
            for (int i = 0; i < 2; ++i)
                acc[i][j] = mfma16(fah[i], bh, acc[i][j]);
            if constexpr (MODE) {
                #pragma unroll
                for (int i = 0; i < 2; ++i)
                    acc[i][j] = mfma16(fal[i], bh, acc[i][j]);
            }
        }
        VDRAIN();            // own prefetch landed before buffer becomes readable
        __syncthreads();     // publish cur^1; all reads of cur done
        cur ^= 1;
    }

    // C/D frag: row = (lane>>4)*4 + r, col = lane&15
    #pragma unroll
    for (int i = 0; i < 2; ++i) {
        const int gr = m0 + wm * 32 + i * 16 + (lane >> 4) * 4;
        #pragma unroll
        for (int j = 0; j < 4; ++j) {
            const int wc = n0 + wn * 64 + j * 16 + (lane & 15);
            #pragma unroll
            for (int r = 0; r < 4; ++r) {
                const size_t ad = ((size_t)bc * F_ + gr + r) * W_ + wc;
                if constexpr (MODE == 1) Fout[ad] = acc[i][j][r];
                else                     Vout[ad] = f2bf(acc[i][j][r]);
            }
        }
    }

    if constexpr (MODE == 0) {
        // rope in-register, per-wave LDS transpose (wave owns 32 dd x 64 w),
        // write q_t[bc][head][w][dd].  M-tile (64) == one head: head = blockIdx.x.
        __syncthreads();                      // staging LDS dead
        u16* Qt = sh + wid * 2048;            // [64 w][32 dd], slot ^= wl&3
        const int head = blockIdx.x;
        #pragma unroll
        for (int j = 0; j < 4; ++j) {
            const int wl = j * 16 + (lane & 15);
            const int wg = n0 + wn * 64 + wl;
            #pragma unroll
            for (int i = 0; i < 2; ++i) {
                float q[4];
                if (wm == 0) {                // dd < 32: rotate
                    #pragma unroll
                    for (int p = 0; p < 2; ++p) {
                        const int fidx = i * 8 + (lane >> 4) * 2 + p;
                        float2 cs = trig[wg * NFREQ_ + fidx];
                        float e = acc[i][j][2 * p], o = acc[i][j][2 * p + 1];
                        q[2 * p]     = (e * cs.x - o * cs.y) * QSC_;
                        q[2 * p + 1] = (o * cs.x + e * cs.y) * QSC_;
                    }
                } else {
                    #pragma unroll
                    for (int r = 0; r < 4; ++r) q[r] = acc[i][j][r] * QSC_;
                }
                #pragma unroll
                for (int r = 0; r < 4; ++r) {
                    const int ddl = i * 16 + (lane >> 4) * 4 + r;     // [0,32)
                    Qt[wl * 32 + ((ddl & 7) | (((ddl >> 3) ^ (wl & 3)) << 3))] = f2bf(q[r]);
                }
            }
        }
        // same-wave read-back (compiler orders lgkmcnt), 16B writes
        const size_t qrow = (((size_t)bc * NH_ + head) * W_ + n0 + wn * 64 + lane) * 64 + wm * 32;
        #pragma unroll
        for (int s = 0; s < 4; ++s) {
            uint4 v = *(const uint4*)(&Qt[lane * 32 + ((s ^ (lane & 3)) << 3)]);
            *(uint4*)(&Qout[qrow + s * 8]) = v;
        }
    }
}

// ---------------- transposed 32x32-MFMA flash attention, 2 q-sets/wave ----------------
// K,V tiles in LDS (dbuf, 32 KB); each wave computes 64 q-cols as two 32-col sets
// sharing every K/V fragment read -> mfma:ds_read = 2:1 (was 1:1 in attn3).
// 2-wave blocks, 128 q-cols/block; grid (8, NH, BC) = 512 -> 4 blocks/CU.
// p = exp2(s) (scale folded into Q/K); writes a_t hi only: [bc][w][512].
__global__ __launch_bounds__(128)
void attn5(const u16* __restrict__ Qt, const u16* __restrict__ Vg,
           u16* __restrict__ AhO)
{
    __shared__ u16 sh[16384];      // 2 bufs x (Ks[64][64] | Vs[64][64]), slot^(row&7)
    const int tid = threadIdx.x, lane = tid & 63, wid = tid >> 6;   // wid 0..1
    const int q0 = blockIdx.x * 128, head = blockIdx.y, bc = blockIdx.z;
    const u16* qb = Qt + ((size_t)bc * NH_ + head) * W_ * 64;
    const u16* vb = Vg + ((size_t)bc * F_ + head * HD_) * W_;

    const int qcol = lane & 31, hi = lane >> 5;
    const int srow = lane >> 3, st = lane & 7;

    // two q-sets per wave: qA = q0 + wid*64 + qcol, qB = qA + 32
    bf16x8 qfA[4], qfB[4];
    {
        const u16* qra = qb + (size_t)(q0 + wid * 64 + qcol) * 64 + hi * 8;
        const u16* qrb = qra + 32 * 64;
        #pragma unroll
        for (int ks = 0; ks < 4; ++ks) {
            qfA[ks] = *(const bf16x8*)(qra + ks * 16);
            qfB[ks] = *(const bf16x8*)(qrb + ks * 16);
        }
    }

    f32x16 oA0, oA1, oB0, oB1;
    #pragma unroll
    for (int i = 0; i < 16; ++i) { oA0[i]=0.f; oA1[i]=0.f; oB0[i]=0.f; oB1[i]=0.f; }
    float lsumA = 0.f, lsumB = 0.f;

    auto STAGE = [&](int kt, int buf) {
        const int k0 = kt * 64;
        u16* Ksb = sh + buf * 8192;
        u16* Vsb = Ksb + 4096;
        #pragma unroll
        for (int p = 0; p < 4; ++p) {
            const int rb = wid * 32 + p * 8;          // wave-uniform
            const int r  = rb + srow;
            const int ts = st ^ (r & 7);
            gload16(qb + (size_t)(k0 + r) * 64 + ts * 8, Ksb + rb * 64);
            gload16(vb + (size_t)r * W_ + k0 + ts * 8,   Vsb + rb * 64);
        }
    };

    STAGE(0, 0);
    VDRAIN();                 // own DMA (and qf loads) landed
    __syncthreads();          // publish buf 0
    int cur = 0;
    for (int kt = 0; kt < 16; ++kt) {
        if (kt < 15) STAGE(kt + 1, cur ^ 1);   // prefetch flies during compute
        const u16* Ks = sh + cur * 8192;
        const u16* Vs = Ks + 4096;

        // S^T = K . Q^T over d (4 K=16 steps); kf reads shared by both q-sets
        f32x16 sA0, sA1, sB0, sB1;
        #pragma unroll
        for (int i = 0; i < 16; ++i) { sA0[i]=0.f; sA1[i]=0.f; sB0[i]=0.f; sB1[i]=0.f; }
        #pragma unroll
        for (int ks = 0; ks < 4; ++ks) {
            const int sl = ks * 2 + hi;
            const int kA = qcol, kB = 32 + qcol;
            bf16x8 kf0 = *(const bf16x8*)(Ks + kA * 64 + ((sl ^ (kA & 7)) << 3));
            bf16x8 kf1 = *(const bf16x8*)(Ks + kB * 64 + ((sl ^ (kB & 7)) << 3));
            sA0 = mfma32(kf0, qfA[ks], sA0);
            sA1 = mfma32(kf1, qfA[ks], sA1);
            sB0 = mfma32(kf0, qfB[ks], sB0);
            sB1 = mfma32(kf1, qfB[ks], sB1);
        }

        // p = exp2(s) in place; accumulate denominators
        #pragma unroll
        for (int i = 0; i < 16; ++i) {
            sA0[i] = EXP2(sA0[i]); sA1[i] = EXP2(sA1[i]);
            sB0[i] = EXP2(sB0[i]); sB1[i] = EXP2(sB1[i]);
        }
        float pa = 0.f, pb = 0.f;
        #pragma unroll
        for (int i = 0; i < 16; ++i) { pa += sA0[i] + sA1[i]; pb += sB0[i] + sB1[i]; }
        lsumA += pa; lsumB += pb;

        // P^T B-frags in-register (cvt_pk + permlane32_swap)
        bf16x8 pfA[4], pfB[4];
        auto PACK = [&](const f32x16& pp, bf16x8* dst) {
            #pragma unroll
            for (int f = 0; f < 2; ++f) {
                u32 a1 = pk2(pp[f*8+0], pp[f*8+1]);
                u32 a2 = pk2(pp[f*8+2], pp[f*8+3]);
                u32 b1 = pk2(pp[f*8+4], pp[f*8+5]);
                u32 b2 = pk2(pp[f*8+6], pp[f*8+7]);
                pl32swap(a1, b1);
                pl32swap(a2, b2);
                union { u32 w[4]; bf16x8 v; } u;
                u.w[0] = a1; u.w[1] = a2; u.w[2] = b1; u.w[3] = b2;
                dst[f] = u.v;
            }
        };
        PACK(sA0, pfA); PACK(sA1, pfA + 2);
        PACK(sB0, pfB); PACK(sB1, pfB + 2);

        // O^T += V^T . P^T ; vf reads shared by both q-sets
        #pragma unroll
        for (int ks2 = 0; ks2 < 4; ++ks2) {
            const int sl = ks2 * 2 + hi;
            const int d0r = qcol, d1r = 32 + qcol;
            bf16x8 vf0 = *(const bf16x8*)(Vs + d0r * 64 + ((sl ^ (d0r & 7)) << 3));
            bf16x8 vf1 = *(const bf16x8*)(Vs + d1r * 64 + ((sl ^ (d1r & 7)) << 3));
            oA0 = mfma32(vf0, pfA[ks2], oA0);
            oA1 = mfma32(vf1, pfA[ks2], oA1);
            oB0 = mfma32(vf0, pfB[ks2], oB0);
            oB1 = mfma32(vf1, pfB[ks2], oB1);
        }
        VDRAIN();            // own prefetch landed before buffer becomes readable
        __syncthreads();     // publish cur^1; all reads of cur done
        cur ^= 1;
    }

    lsumA += __shfl_xor(lsumA, 32);
    lsumB += __shfl_xor(lsumB, 32);
    const float invA = 1.f / lsumA, invB = 1.f / lsumB;

    #pragma unroll
    for (int qs = 0; qs < 2; ++qs) {
        const float inv = qs ? invB : invA;
        const int wrow = q0 + wid * 64 + qs * 32 + qcol;
        const size_t rowbase = ((size_t)bc * W_ + wrow) * F_ + head * HD_;
        #pragma unroll
        for (int dblk = 0; dblk < 2; ++dblk) {
            const f32x16 ov = qs ? (dblk ? oB1 : oB0) : (dblk ? oA1 : oA0);
            const int coloff = dblk * 32;
            #pragma unroll
            for (int pr = 0; pr < 8; ++pr) {      // reg pair (2pr,2pr+1) -> d rows
                const float v1 = ov[2 * pr]     * inv;
                const float v2 = ov[2 * pr + 1] * inv;
                const int drow = ((2 * pr) & 3) + 8 * (pr >> 1) + 4 * hi;
                const u16 h1 = f2bf(v1), h2 = f2bf(v2);
                *(u32*)(AhO + rowbase + coloff + drow) = (u32)h1 | ((u32)h2 << 16);
            }
        }
    }
}

extern "C" void kernel_launch(void* const* d_in, const int* in_sizes, int n_in,
                              void* d_out, int out_size, void* d_ws, size_t ws_size,
                              hipStream_t stream) {
    const float* x  = (const float*)d_in[0];
    const float* wq = (const float*)d_in[1];   // reference: q, k, v ALL from wq
    const float* wo = (const float*)d_in[4];
    const float* fp = (const float*)d_in[5];
    float* out = (float*)d_out;

    char* w8 = (char*)d_ws;
    const size_t MB = 1024 * 1024;
    u16* xh   = (u16*)(w8);                    // 8 MB  x_t[bc][w][h] bf16
    u16* wqh  = (u16*)(w8 + 8 * MB);           // 1 MB
    u16* woh  = (u16*)(w8 + 9 * MB);           // 1 MB
    u16* wol  = (u16*)(w8 + 10 * MB);          // 1 MB
    float2* trig = (float2*)(w8 + 11 * MB);    // 128 KB
    u16* qbuf = (u16*)(w8 + 12 * MB);          // 8 MB  q_t[bc][head][w][64]
    u16* vbuf = (u16*)(w8 + 20 * MB);          // 8 MB  v[bc][g][w]
    u16* ah   = xh;                            // alias: x_t dead after proj GEMM

    prep_all<<<2112, 256, 0, stream>>>(wq, wo, fp, x, wqh, woh, wol, trig, xh);

    gemm4<0><<<dim3(8, 8, 8), 256, 0, stream>>>(
        wqh, nullptr, xh, vbuf, qbuf, nullptr, trig);

    attn5<<<dim3(8, NH_, BC_), 128, 0, stream>>>(qbuf, vbuf, ah);

    gemm4<1><<<dim3(8, 8, 8), 256, 0, stream>>>(
        woh, wol, ah, nullptr, nullptr, out, trig);
}